// Round 1
// baseline (1125.526 us; speedup 1.0000x reference)
//
#include <hip/hip_runtime.h>
#include <hip/hip_bf16.h>

// out[b, p] = req_to_token[req_pool_indices[b], p*PAGE_SIZE] / PAGE_SIZE
//             for p < ceil(page_kernel_lens[b] / PAGE_SIZE); else 0.
//
// Shapes (static): req_to_token [4096, 65536] i32, req_pool_indices [1024] i32,
// page_kernel_lens [1024] i32, out [1024, 1024] i32.

#define PAGE_SIZE   64
#define PAGE_SHIFT  6
#define MAX_CTX     65536
#define MAX_PAGES   1024
#define BATCH       1024

__global__ __launch_bounds__(256)
void kv_page_index_kernel(const int* __restrict__ req_to_token,
                          const int* __restrict__ req_pool_indices,
                          const int* __restrict__ page_kernel_lens,
                          int* __restrict__ out) {
    const int b = blockIdx.y;                       // batch row (uniform per block)
    const int p = blockIdx.x * blockDim.x + threadIdx.x;  // page id

    // Uniform per block -> compiler emits scalar loads.
    const int row = req_pool_indices[b];
    const int len = page_kernel_lens[b];
    const int num_pages = (len + PAGE_SIZE - 1) >> PAGE_SHIFT;

    int v = 0;
    if (p < num_pages) {
        // stride-64 element gather within the row; values are < 2^28 (non-negative)
        const size_t idx = (size_t)row * MAX_CTX + ((size_t)p << PAGE_SHIFT);
        v = req_to_token[idx] >> PAGE_SHIFT;
    }
    out[(size_t)b * MAX_PAGES + p] = v;             // coalesced; also zeros the masked tail
}

extern "C" void kernel_launch(void* const* d_in, const int* in_sizes, int n_in,
                              void* d_out, int out_size, void* d_ws, size_t ws_size,
                              hipStream_t stream) {
    const int* req_to_token     = (const int*)d_in[0];
    const int* req_pool_indices = (const int*)d_in[1];
    const int* page_kernel_lens = (const int*)d_in[2];
    int* out = (int*)d_out;

    dim3 block(256, 1, 1);
    dim3 grid(MAX_PAGES / 256, BATCH, 1);           // (4, 1024)
    kv_page_index_kernel<<<grid, block, 0, stream>>>(
        req_to_token, req_pool_indices, page_kernel_lens, out);
}